// Round 13
// baseline (1962.853 us; speedup 1.0000x reference)
//
#include <hip/hip_runtime.h>
#include <hip/hip_bf16.h>
#include <math.h>

#define VOCAB 6500
#define EMB   192
#define NH    6
#define NL    6
#define SEQ   512
#define BATCH 32
#define HSZ   32
#define BT    (BATCH*SEQ)   // 16384 tokens
#define NBLK  512           // 2 blocks/CU x 256 CUs: co-resident with VGPR<=128

typedef __attribute__((ext_vector_type(8))) short bh8;
typedef __attribute__((ext_vector_type(4))) float f32x4;

// q pre-scale folds softmax scale AND log2(e): exp(s*c) == exp2(s*c*log2e)
#define ATT_SCALE_L2E 0.10413996713994119f   // 192^-0.5 * 1.4426950408889634
static constexpr size_t NTE = (size_t)BT * EMB;

static __device__ __forceinline__ short bf16s(float v) {
  __hip_bfloat16 t = __float2bfloat16(v);
  return *reinterpret_cast<short*>(&t);
}

// ---------------------------------------------------------------- global barrier (512 blocks)
// layout per barrier: [16 arrive][root@16][pad][16 release@24..39], 48 ints
// poll with LOADS (broadcastable), never RMW (round-10 lesson)
static __device__ __forceinline__ void gbar(int* base) {
  __syncthreads();
  if (threadIdx.x == 0) {
    __threadfence();
    const int grp = blockIdx.x & 15;
    if (atomicAdd(base + grp, 1) == 31) {        // last of my 32-block group
      if (atomicAdd(base + 16, 1) == 15) {       // last group: release everyone
        __threadfence();
        #pragma unroll
        for (int g2 = 0; g2 < 16; ++g2)
          __hip_atomic_store(base + 24 + g2, 1, __ATOMIC_RELAXED,
                             __HIP_MEMORY_SCOPE_AGENT);
      }
    }
    int guard = 0;
    while (__hip_atomic_load(base + 24 + grp, __ATOMIC_RELAXED,
                             __HIP_MEMORY_SCOPE_AGENT) == 0) {
      __builtin_amdgcn_s_sleep(8);
      if (++guard > (1 << 20)) break;            // fail loud (absmax), never hang
    }
    __threadfence();
  }
  __syncthreads();
}

// ---------------------------------------------------------------- weight cast job (32x32 tile)
static __device__ __forceinline__ void wprep_job(
    short* smem, int id,
    const float* Wq, const float* Wk, const float* Wv, const float* Wo,
    const float* W1, const float* W2, const float* Wlm,
    __hip_bfloat16* wqkv, __hip_bfloat16* wot, __hip_bfloat16* w1t,
    __hip_bfloat16* w2t, __hip_bfloat16* wlt) {
  float (*t)[33] = (float(*)[33])smem;
  const float* Ws; __hip_bfloat16* Wd; int K, N, bx, by;
  if (id < 864) {
    const int z = id / 36, rem = id % 36;
    const int sel = z / NL, layer = z % NL;
    by = rem / 6; bx = rem % 6; K = 192; N = 192;
    const float* s4[4] = {Wq, Wk, Wv, Wo};
    Ws = s4[sel] + (size_t)layer * 192 * 192;
    Wd = (sel < 3) ? wqkv + ((size_t)layer * 576 + sel * 192) * 192
                   : wot  + (size_t)layer * 192 * 192;
  } else if (id < 1728) {
    const int j = id - 864, layer = j / 144, rem = j % 144;
    bx = rem % 24; by = rem / 24; K = 192; N = 768;
    Ws = W1 + (size_t)layer * 192 * 768;
    Wd = w1t + (size_t)layer * 768 * 192;
  } else if (id < 2592) {
    const int j = id - 1728, layer = j / 144, rem = j % 144;
    bx = rem % 6; by = rem / 6; K = 768; N = 192;
    Ws = W2 + (size_t)layer * 768 * 192;
    Wd = w2t + (size_t)layer * 192 * 768;
  } else {
    const int j = id - 2592;
    bx = j % 204; by = j / 204; K = 192; N = VOCAB;
    Ws = Wlm; Wd = wlt;
  }
  const int kt = by * 32, nt = bx * 32;
  const int tx = threadIdx.x & 31, ty = threadIdx.x >> 5;
  __syncthreads();
  for (int i = ty; i < 32; i += 8) {
    const int k = kt + i, n = nt + tx;
    t[i][tx] = (k < K && n < N) ? Ws[(size_t)k * N + n] : 0.f;
  }
  __syncthreads();
  for (int i = ty; i < 32; i += 8) {
    const int n = nt + i, k = kt + tx;
    if (n < N && k < K) Wd[(size_t)n * K + k] = __float2bfloat16(t[tx][i]);
  }
}

// ---------------------------------------------------------------- embed + PE + LN1(l0), 4 tokens/job
static __device__ __forceinline__ void embed_job(
    int j, const int* idx, const float* tok, const float* g, const float* b,
    float* x, __hip_bfloat16* h) {
  const int wid = threadIdx.x >> 6, lane = threadIdx.x & 63;
  const int bt = j * 4 + wid;
  const int t = bt & (SEQ - 1);
  const int tokid = idx[bt];
  float v[3];
  #pragma unroll
  for (int i = 0; i < 3; ++i) {
    const int e = lane + i * 64;
    const int i2 = e & ~1;
    const float div = expf((float)i2 * (-9.210340371976184f / (float)EMB));
    const float ang = (float)t * div;
    const float pe = (e & 1) ? cosf(ang) : sinf(ang);
    v[i] = tok[(size_t)tokid * EMB + e] + pe;
  }
  float s = v[0] + v[1] + v[2];
  #pragma unroll
  for (int o = 32; o; o >>= 1) s += __shfl_xor(s, o);
  const float mu = s * (1.0f / (float)EMB);
  float vs = 0.f;
  #pragma unroll
  for (int i = 0; i < 3; ++i) { const float d = v[i] - mu; vs += d * d; }
  #pragma unroll
  for (int o = 32; o; o >>= 1) vs += __shfl_xor(vs, o);
  const float r = rsqrtf(vs * (1.0f / (float)EMB) + 1e-5f);
  #pragma unroll
  for (int i = 0; i < 3; ++i) {
    const int e = lane + i * 64;
    x[(size_t)bt * EMB + e] = v[i];
    h[(size_t)bt * EMB + e] = __float2bfloat16((v[i] - mu) * r * g[e] + b[e]);
  }
}

// ---------------------------------------------------------------- 128x64 GEMM tile, prefetched
// EPI 0: f32; EPI 2: gelu->bf16; EPI 3: qkv scatter (q pre-scaled by ATT_SCALE_L2E)
template<int EPI>
static __device__ __forceinline__ void gemm_tile(
    short* smem, const __hip_bfloat16* A, const __hip_bfloat16* Bt,
    void* Cv, int m0, int n0, int N, int K) {
  constexpr int LDK = 72;
  short* As = smem;                 // [128][72]
  short* Bs = smem + 128 * LDK;     // [64][72]
  const int tid = threadIdx.x;
  const int wid = tid >> 6, lane = tid & 63;
  const int srow = tid >> 3, schk = tid & 7;
  const int fr = lane & 15, fg = lane >> 4;

  f32x4 acc[2][4];
  #pragma unroll
  for (int rt = 0; rt < 2; ++rt)
    #pragma unroll
    for (int ct = 0; ct < 4; ++ct) acc[rt][ct] = (f32x4){0.f, 0.f, 0.f, 0.f};

  bh8 av[4], bv[2];
  #pragma unroll
  for (int p = 0; p < 4; ++p)
    av[p] = *(const bh8*)(A + (size_t)(m0 + srow + p * 32) * K + schk * 8);
  #pragma unroll
  for (int p = 0; p < 2; ++p) {
    const int nr = n0 + srow + p * 32;
    if (nr < N) bv[p] = *(const bh8*)(Bt + (size_t)nr * K + schk * 8);
    else        bv[p] = (bh8){0,0,0,0,0,0,0,0};
  }

  for (int k0 = 0; k0 < K; k0 += 64) {
    __syncthreads();
    #pragma unroll
    for (int p = 0; p < 4; ++p)
      *(bh8*)(As + (srow + p * 32) * LDK + schk * 8) = av[p];
    #pragma unroll
    for (int p = 0; p < 2; ++p)
      *(bh8*)(Bs + (srow + p * 32) * LDK + schk * 8) = bv[p];
    __syncthreads();
    if (k0 + 64 < K) {
      const int kn = k0 + 64 + schk * 8;
      #pragma unroll
      for (int p = 0; p < 4; ++p)
        av[p] = *(const bh8*)(A + (size_t)(m0 + srow + p * 32) * K + kn);
      #pragma unroll
      for (int p = 0; p < 2; ++p) {
        const int nr = n0 + srow + p * 32;
        if (nr < N) bv[p] = *(const bh8*)(Bt + (size_t)nr * K + kn);
      }
    }
    #pragma unroll
    for (int s = 0; s < 2; ++s) {
      bh8 af[2];
      #pragma unroll
      for (int rt = 0; rt < 2; ++rt)
        af[rt] = *(const bh8*)(As + (wid * 32 + rt * 16 + fr) * LDK + s * 32 + fg * 8);
      #pragma unroll
      for (int ct = 0; ct < 4; ++ct) {
        const bh8 bf_ = *(const bh8*)(Bs + (ct * 16 + fr) * LDK + s * 32 + fg * 8);
        #pragma unroll
        for (int rt = 0; rt < 2; ++rt)
          acc[rt][ct] = __builtin_amdgcn_mfma_f32_16x16x32_bf16(af[rt], bf_, acc[rt][ct], 0, 0, 0);
      }
    }
  }

  #pragma unroll
  for (int rt = 0; rt < 2; ++rt)
    #pragma unroll
    for (int ct = 0; ct < 4; ++ct) {
      const int col = n0 + ct * 16 + fr;
      if (col < N) {
        #pragma unroll
        for (int rr = 0; rr < 4; ++rr) {
          const int row = m0 + wid * 32 + rt * 16 + fg * 4 + rr;
          float v = acc[rt][ct][rr];
          if (EPI == 0) {
            ((float*)Cv)[(size_t)row * N + col] = v;
          } else if (EPI == 2) {
            v = 0.5f * v * (1.0f + erff(v * 0.70710678118654752f));
            ((__hip_bfloat16*)Cv)[(size_t)row * N + col] = __float2bfloat16(v);
          } else {
            const int part = col / 192, c2 = col - part * 192;
            if (part == 0) v *= ATT_SCALE_L2E;
            const int bb = row >> 9, tt = row & (SEQ - 1);
            const int hh = c2 >> 5, dd = c2 & (HSZ - 1);
            ((__hip_bfloat16*)Cv)[(size_t)part * NTE +
                (((size_t)(bb * NH + hh)) * SEQ + tt) * HSZ + dd] = __float2bfloat16(v);
          }
        }
      }
    }
}

// ---------------------------------------------------------------- resLN tile, BM=16, 4 waves col-split
static __device__ __forceinline__ void resln_tile(
    short* smem, const __hip_bfloat16* A, const __hip_bfloat16* Bt,
    float* X, __hip_bfloat16* Hout, const float* g, const float* b,
    int m0, int K) {
  constexpr int LDK = 72;
  short* As = smem;                        // [16][72]
  short* Bs = smem + 16 * LDK;             // [192][72]
  float* red = (float*)(smem + (16 + 192) * LDK);  // [4][16][2]
  const int tid = threadIdx.x;
  const int wid = tid >> 6, lane = tid & 63;
  const int srow = tid >> 3, schk = tid & 7;
  const int fr = lane & 15, fg = lane >> 4;

  f32x4 acc[3];
  #pragma unroll
  for (int c = 0; c < 3; ++c) acc[c] = (f32x4){0.f, 0.f, 0.f, 0.f};

  bh8 av = (bh8){0,0,0,0,0,0,0,0}, bv[6];
  if (srow < 16) av = *(const bh8*)(A + (size_t)(m0 + srow) * K + schk * 8);
  #pragma unroll
  for (int p = 0; p < 6; ++p)
    bv[p] = *(const bh8*)(Bt + (size_t)(srow + p * 32) * K + schk * 8);

  for (int k0 = 0; k0 < K; k0 += 64) {
    __syncthreads();
    if (srow < 16) *(bh8*)(As + srow * LDK + schk * 8) = av;
    #pragma unroll
    for (int p = 0; p < 6; ++p)
      *(bh8*)(Bs + (srow + p * 32) * LDK + schk * 8) = bv[p];
    __syncthreads();
    if (k0 + 64 < K) {
      const int kn = k0 + 64 + schk * 8;
      if (srow < 16) av = *(const bh8*)(A + (size_t)(m0 + srow) * K + kn);
      #pragma unroll
      for (int p = 0; p < 6; ++p)
        bv[p] = *(const bh8*)(Bt + (size_t)(srow + p * 32) * K + kn);
    }
    #pragma unroll
    for (int s = 0; s < 2; ++s) {
      const bh8 af = *(const bh8*)(As + fr * LDK + s * 32 + fg * 8);
      #pragma unroll
      for (int c = 0; c < 3; ++c) {
        const bh8 bf_ = *(const bh8*)(Bs + ((wid * 3 + c) * 16 + fr) * LDK + s * 32 + fg * 8);
        acc[c] = __builtin_amdgcn_mfma_f32_16x16x32_bf16(af, bf_, acc[c], 0, 0, 0);
      }
    }
  }

  float v[4][3], ps[4], pq[4];
  #pragma unroll
  for (int rr = 0; rr < 4; ++rr) {
    const int row = m0 + fg * 4 + rr;
    float s = 0.f, q = 0.f;
    #pragma unroll
    for (int c = 0; c < 3; ++c) {
      const int col = (wid * 3 + c) * 16 + fr;
      const float t = acc[c][rr] + X[(size_t)row * EMB + col];
      v[rr][c] = t; s += t; q += t * t;
    }
    #pragma unroll
    for (int o = 8; o; o >>= 1) { s += __shfl_xor(s, o); q += __shfl_xor(q, o); }
    ps[rr] = s; pq[rr] = q;
  }
  if (fr == 0) {
    #pragma unroll
    for (int rr = 0; rr < 4; ++rr) {
      red[(wid * 16 + fg * 4 + rr) * 2 + 0] = ps[rr];
      red[(wid * 16 + fg * 4 + rr) * 2 + 1] = pq[rr];
    }
  }
  __syncthreads();
  #pragma unroll
  for (int rr = 0; rr < 4; ++rr) {
    const int row2 = fg * 4 + rr;
    float s = 0.f, q = 0.f;
    #pragma unroll
    for (int w = 0; w < 4; ++w) {
      s += red[(w * 16 + row2) * 2];
      q += red[(w * 16 + row2) * 2 + 1];
    }
    const float mu = s * (1.0f / (float)EMB);
    const float r = rsqrtf(q * (1.0f / (float)EMB) - mu * mu + 1e-5f);
    const int row = m0 + row2;
    #pragma unroll
    for (int c = 0; c < 3; ++c) {
      const int col = (wid * 3 + c) * 16 + fr;
      const float t = v[rr][c];
      X[(size_t)row * EMB + col] = t;
      Hout[(size_t)row * EMB + col] = __float2bfloat16((t - mu) * r * g[col] + b[col]);
    }
  }
}

// ---------------------------------------------------------------- flash attn job, KT=64, exp2 softmax
static __device__ __forceinline__ void attn_job(
    short* smem, const __hip_bfloat16* qh, const __hip_bfloat16* kh,
    const __hip_bfloat16* vh, __hip_bfloat16* att, int qt, int hd, int bb) {
  constexpr int LDP = 72;
  short* Ks = smem;                  // [64][72]
  short* Vs = smem + 64 * LDP;       // [32][72]
  short* Ps = smem + 96 * LDP;       // [4][32][72]
  const int tid = threadIdx.x, wid = tid >> 6, lane = tid & 63;
  const int q0 = qt * 128;
  const size_t hb = ((size_t)(bb * NH + hd)) * SEQ * HSZ;
  const int fr = lane & 15, fg = lane >> 4;

  bh8 aq[2];
  #pragma unroll
  for (int rt = 0; rt < 2; ++rt)
    aq[rt] = *(const bh8*)(qh + hb + (size_t)(q0 + wid * 32 + rt * 16 + fr) * HSZ + fg * 8);

  f32x4 o[2][2];
  float lp[2][4];
  #pragma unroll
  for (int rt = 0; rt < 2; ++rt) {
    #pragma unroll
    for (int ct = 0; ct < 2; ++ct) o[rt][ct] = (f32x4){0.f, 0.f, 0.f, 0.f};
    #pragma unroll
    for (int rr = 0; rr < 4; ++rr) lp[rt][rr] = 0.f;
  }

  const int nt = 2 * qt + 2;
  const int sr = tid >> 2, d0 = (tid & 3) * 8;
  bh8 kv = *(const bh8*)(kh + hb + (size_t)sr * HSZ + d0);
  bh8 vv = *(const bh8*)(vh + hb + (size_t)sr * HSZ + d0);

  for (int it = 0; it < nt; ++it) {
    const int s0 = it * 64;
    __syncthreads();
    {
      *(bh8*)(Ks + sr * LDP + d0) = kv;
      short tmp[8]; *(bh8*)tmp = vv;
      #pragma unroll
      for (int jj = 0; jj < 8; ++jj) Vs[(d0 + jj) * LDP + sr] = tmp[jj];
    }
    __syncthreads();
    if (it + 1 < nt) {
      const size_t nb_ = hb + (size_t)(s0 + 64 + sr) * HSZ + d0;
      kv = *(const bh8*)(kh + nb_);
      vv = *(const bh8*)(vh + nb_);
    }

    f32x4 sfr[2][4];
    #pragma unroll
    for (int rt = 0; rt < 2; ++rt)
      #pragma unroll
      for (int st = 0; st < 4; ++st) {
        const bh8 bf_ = *(const bh8*)(Ks + (st * 16 + fr) * LDP + fg * 8);
        sfr[rt][st] = __builtin_amdgcn_mfma_f32_16x16x32_bf16(
            aq[rt], bf_, (f32x4){0.f, 0.f, 0.f, 0.f}, 0, 0, 0);
      }

    short* Pw = Ps + wid * 32 * LDP;
    const bool diag = (s0 + 63 > q0 + wid * 32);
    #pragma unroll
    for (int rt = 0; rt < 2; ++rt) {
      #pragma unroll
      for (int rr = 0; rr < 4; ++rr) {
        float pr[4];
        if (diag) {
          const int qa = q0 + wid * 32 + rt * 16 + fg * 4 + rr;
          #pragma unroll
          for (int st = 0; st < 4; ++st) {
            const int sa = s0 + st * 16 + fr;
            pr[st] = (sa > qa) ? 0.f : exp2f(sfr[rt][st][rr]);
          }
        } else {
          #pragma unroll
          for (int st = 0; st < 4; ++st) pr[st] = exp2f(sfr[rt][st][rr]);
        }
        lp[rt][rr] += (pr[0] + pr[1]) + (pr[2] + pr[3]);
        #pragma unroll
        for (int st = 0; st < 4; ++st)
          Pw[(rt * 16 + fg * 4 + rr) * LDP + st * 16 + fr] = bf16s(pr[st]);
      }
    }

    #pragma unroll
    for (int ks = 0; ks < 2; ++ks) {
      bh8 vb_[2];
      #pragma unroll
      for (int ct = 0; ct < 2; ++ct)
        vb_[ct] = *(const bh8*)(Vs + (ct * 16 + fr) * LDP + ks * 32 + fg * 8);
      #pragma unroll
      for (int rt = 0; rt < 2; ++rt) {
        const bh8 pa = *(const bh8*)(Pw + (rt * 16 + fr) * LDP + ks * 32 + fg * 8);
        #pragma unroll
        for (int ct = 0; ct < 2; ++ct)
          o[rt][ct] = __builtin_amdgcn_mfma_f32_16x16x32_bf16(pa, vb_[ct], o[rt][ct], 0, 0, 0);
      }
    }
  }

  #pragma unroll
  for (int rt = 0; rt < 2; ++rt)
    #pragma unroll
    for (int rr = 0; rr < 4; ++rr) {
      float s = lp[rt][rr];
      #pragma unroll
      for (int off = 8; off; off >>= 1) s += __shfl_xor(s, off);
      const float inv = 1.0f / s;
      const int qa = q0 + wid * 32 + rt * 16 + fg * 4 + rr;
      #pragma unroll
      for (int ct = 0; ct < 2; ++ct) {
        const int d = ct * 16 + fr;
        att[((size_t)(bb * SEQ + qa)) * EMB + hd * HSZ + d] =
            __float2bfloat16(o[rt][ct][rr] * inv);
      }
    }
}

// ---------------------------------------------------------------- persistent mega-kernel
// min 2 waves/EU -> VGPR cap 128 (round-10/11 used ",4" -> 64 VGPR -> scratch spills)
__global__ __launch_bounds__(256, 2) void mega(
    const int* idx, const float* tok,
    const float* Wq, const float* Wk, const float* Wv, const float* Wo,
    const float* W1, const float* W2, const float* Wlm,
    const float* ln1g, const float* ln1b, const float* ln2g, const float* ln2b,
    const float* lnfg, const float* lnfb,
    float* x, __hip_bfloat16* qh, __hip_bfloat16* h, __hip_bfloat16* att,
    __hip_bfloat16* hid, __hip_bfloat16* wqkv, __hip_bfloat16* wot,
    __hip_bfloat16* w1t, __hip_bfloat16* w2t, __hip_bfloat16* wlt,
    float* out, int* bars) {
  __shared__ __align__(16) short smem[16128];   // 32.25 KB union -> 2 blocks/CU
  const int bid = blockIdx.x;
  int bar = 0;

  // phase 0: weight casts + embed/PE/LN1
  for (int j = bid; j < 3816; j += NBLK)
    wprep_job(smem, j, Wq, Wk, Wv, Wo, W1, W2, Wlm, wqkv, wot, w1t, w2t, wlt);
  for (int j = bid; j < BT / 4; j += NBLK)
    embed_job(j, idx, tok, ln1g, ln1b, x, h);
  gbar(bars + (bar++) * 48);

  for (int l = 0; l < NL; ++l) {
    const __hip_bfloat16* wq_l = wqkv + (size_t)l * 576 * EMB;
    for (int j = bid; j < 1152; j += NBLK)
      gemm_tile<3>(smem, h, wq_l, qh, (j / 9) * 128, (j % 9) * 64, 576, EMB);
    gbar(bars + (bar++) * 48);

    for (int j = bid; j < 768; j += NBLK) {
      const int qi = j & 3, hh = (j >> 2) % 6, bb = j / 24;
      attn_job(smem, qh, qh + NTE, qh + 2 * NTE, att, 3 - qi, hh, bb);
    }
    gbar(bars + (bar++) * 48);

    for (int j = bid; j < 1024; j += NBLK)
      resln_tile(smem, att, wot + (size_t)l * EMB * EMB, x, h,
                 ln2g + l * EMB, ln2b + l * EMB, j * 16, EMB);
    gbar(bars + (bar++) * 48);

    for (int j = bid; j < 1536; j += NBLK)
      gemm_tile<2>(smem, h, w1t + (size_t)l * EMB * EMB * 4, hid,
                   (j / 12) * 128, (j % 12) * 64, EMB * 4, EMB);
    gbar(bars + (bar++) * 48);

    const float* ng = (l == NL - 1) ? lnfg : ln1g + (l + 1) * EMB;
    const float* nb = (l == NL - 1) ? lnfb : ln1b + (l + 1) * EMB;
    for (int j = bid; j < 1024; j += NBLK)
      resln_tile(smem, hid, w2t + (size_t)l * EMB * EMB * 4, x, h,
                 ng, nb, j * 16, EMB * 4);
    gbar(bars + (bar++) * 48);
  }

  for (int j = bid; j < 13056; j += NBLK)
    gemm_tile<0>(smem, h, wlt, out, (j / 102) * 128, (j % 102) * 64, VOCAB, EMB);
}

// ---------------------------------------------------------------- launcher
extern "C" void kernel_launch(void* const* d_in, const int* in_sizes, int n_in,
                              void* d_out, int out_size, void* d_ws, size_t ws_size,
                              hipStream_t stream) {
  const int*   idx   = (const int*)  d_in[0];
  const float* tok   = (const float*)d_in[1];
  const float* Wq    = (const float*)d_in[2];
  const float* Wk    = (const float*)d_in[3];
  const float* Wv    = (const float*)d_in[4];
  const float* Wo    = (const float*)d_in[5];
  const float* W1    = (const float*)d_in[6];
  const float* W2    = (const float*)d_in[7];
  const float* ln1g  = (const float*)d_in[8];
  const float* ln1b  = (const float*)d_in[9];
  const float* ln2g  = (const float*)d_in[10];
  const float* ln2b  = (const float*)d_in[11];
  const float* lnfg  = (const float*)d_in[12];
  const float* lnfb  = (const float*)d_in[13];
  const float* Wlm   = (const float*)d_in[14];
  float* out = (float*)d_out;

  char* ws = (char*)d_ws;
  int* bars = (int*)ws;                            ws += 8192;
  float* x   = (float*)ws;                         ws += NTE * 4;
  __hip_bfloat16* qh   = (__hip_bfloat16*)ws;      ws += NTE * 2 * 3;
  __hip_bfloat16* h    = (__hip_bfloat16*)ws;      ws += NTE * 2;
  __hip_bfloat16* att  = (__hip_bfloat16*)ws;      ws += NTE * 2;
  __hip_bfloat16* hid  = (__hip_bfloat16*)ws;      ws += NTE * 4 * 2;
  __hip_bfloat16* wqkv = (__hip_bfloat16*)ws;      ws += (size_t)NL * 576 * EMB * 2;
  __hip_bfloat16* wot  = (__hip_bfloat16*)ws;      ws += (size_t)NL * EMB * EMB * 2;
  __hip_bfloat16* w1t  = (__hip_bfloat16*)ws;      ws += (size_t)NL * EMB * EMB * 4 * 2;
  __hip_bfloat16* w2t  = (__hip_bfloat16*)ws;      ws += (size_t)NL * EMB * EMB * 4 * 2;
  __hip_bfloat16* wlt  = (__hip_bfloat16*)ws;

  hipMemsetAsync(bars, 0, 8192, stream);
  mega<<<NBLK, 256, 0, stream>>>(
      idx, tok, Wq, Wk, Wv, Wo, W1, W2, Wlm,
      ln1g, ln1b, ln2g, ln2b, lnfg, lnfb,
      x, qh, h, att, hid, wqkv, wot, w1t, w2t, wlt, out, bars);
}

// Round 14
// 778.565 us; speedup vs baseline: 2.5211x; 2.5211x over previous
//
#include <hip/hip_runtime.h>
#include <hip/hip_bf16.h>
#include <math.h>

#define VOCAB 6500
#define EMB   192
#define NH    6
#define NL    6
#define SEQ   512
#define BATCH 32
#define HSZ   32
#define BT    (BATCH*SEQ)   // 16384 tokens

typedef __attribute__((ext_vector_type(8))) short bh8;
typedef __attribute__((ext_vector_type(4))) float f32x4;

// q pre-scale folds softmax scale AND log2(e): exp(s*c) == exp2(s*c*log2e)
#define ATT_SCALE_L2E 0.10413996713994119f   // 192^-0.5 * 1.4426950408889634

static __device__ __forceinline__ short bf16s(float v) {
  __hip_bfloat16 t = __float2bfloat16(v);
  return *reinterpret_cast<short*>(&t);
}

// ---------------------------------------------------------------- weight prep (all casts, one dispatch)
__global__ __launch_bounds__(256) void wprep(
    const float* __restrict__ Wq, const float* __restrict__ Wk,
    const float* __restrict__ Wv, const float* __restrict__ Wo,
    const float* __restrict__ W1, const float* __restrict__ W2,
    const float* __restrict__ Wlm,
    __hip_bfloat16* __restrict__ wqkv, __hip_bfloat16* __restrict__ wot,
    __hip_bfloat16* __restrict__ w1t,  __hip_bfloat16* __restrict__ w2t,
    __hip_bfloat16* __restrict__ wlt) {
  __shared__ float t[32][33];
  const int id = blockIdx.x;
  const float* Ws; __hip_bfloat16* Wd; int K, N, bx, by;
  if (id < 864) {
    const int z = id / 36, rem = id % 36;
    const int sel = z / NL, layer = z % NL;
    by = rem / 6; bx = rem % 6; K = 192; N = 192;
    const float* s4[4] = {Wq, Wk, Wv, Wo};
    Ws = s4[sel] + (size_t)layer * 192 * 192;
    Wd = (sel < 3) ? wqkv + ((size_t)layer * 576 + sel * 192) * 192
                   : wot  + (size_t)layer * 192 * 192;
  } else if (id < 1728) {
    const int j = id - 864, layer = j / 144, rem = j % 144;
    bx = rem % 24; by = rem / 24; K = 192; N = 768;
    Ws = W1 + (size_t)layer * 192 * 768;
    Wd = w1t + (size_t)layer * 768 * 192;
  } else if (id < 2592) {
    const int j = id - 1728, layer = j / 144, rem = j % 144;
    bx = rem % 6; by = rem / 6; K = 768; N = 192;
    Ws = W2 + (size_t)layer * 768 * 192;
    Wd = w2t + (size_t)layer * 192 * 768;
  } else {
    const int j = id - 2592;
    bx = j % 204; by = j / 204; K = 192; N = VOCAB;
    Ws = Wlm; Wd = wlt;
  }
  const int kt = by * 32, nt = bx * 32;
  const int tx = threadIdx.x & 31, ty = threadIdx.x >> 5;
  for (int i = ty; i < 32; i += 8) {
    const int k = kt + i, n = nt + tx;
    t[i][tx] = (k < K && n < N) ? Ws[(size_t)k * N + n] : 0.f;
  }
  __syncthreads();
  for (int i = ty; i < 32; i += 8) {
    const int n = nt + i, k = kt + tx;
    if (n < N && k < K) Wd[(size_t)n * K + k] = __float2bfloat16(t[tx][i]);
  }
}

// ---------------------------------------------------------------- embed + PE + LN1(layer0)
__global__ __launch_bounds__(256) void embed_ln(
    const int* __restrict__ idx, const float* __restrict__ tok,
    const float* __restrict__ g, const float* __restrict__ b,
    float* __restrict__ x, __hip_bfloat16* __restrict__ h) {
  const int wid = threadIdx.x >> 6, lane = threadIdx.x & 63;
  const int bt = blockIdx.x * 4 + wid;
  const int t  = bt & (SEQ - 1);
  const int tokid = idx[bt];
  float v[3];
  #pragma unroll
  for (int i = 0; i < 3; ++i) {
    const int e = lane + i * 64;
    const int i2 = e & ~1;
    const float div = expf((float)i2 * (-9.210340371976184f / (float)EMB));
    const float ang = (float)t * div;
    const float pe  = (e & 1) ? cosf(ang) : sinf(ang);
    v[i] = tok[(size_t)tokid * EMB + e] + pe;
  }
  float s = v[0] + v[1] + v[2];
  #pragma unroll
  for (int o = 32; o; o >>= 1) s += __shfl_xor(s, o);
  const float mu = s * (1.0f / (float)EMB);
  float vs = 0.f;
  #pragma unroll
  for (int i = 0; i < 3; ++i) { const float d = v[i] - mu; vs += d * d; }
  #pragma unroll
  for (int o = 32; o; o >>= 1) vs += __shfl_xor(vs, o);
  const float r = rsqrtf(vs * (1.0f / (float)EMB) + 1e-5f);
  #pragma unroll
  for (int i = 0; i < 3; ++i) {
    const int e = lane + i * 64;
    x[(size_t)bt * EMB + e] = v[i];
    h[(size_t)bt * EMB + e] = __float2bfloat16((v[i] - mu) * r * g[e] + b[e]);
  }
}

// ---------------------------------------------------------------- big-tile GEMM (BM=128), prefetched
// EPI 0: f32 [M,N];  EPI 3: bf16 qkv scatter (q pre-scaled by ATT_SCALE_L2E)
template<int EPI, int BN>
__global__ __launch_bounds__(256) void gemm_big(
    const __hip_bfloat16* __restrict__ A, const __hip_bfloat16* __restrict__ Bt,
    void* __restrict__ Cv, int M, int N, int K) {
  constexpr int LDK = 72;
  constexpr int NB = BN / 32;
  constexpr int NC = BN / 16;
  __shared__ short As[128 * LDK];
  __shared__ short Bs[BN * LDK];
  const int tid = threadIdx.x;
  const int wid = tid >> 6, lane = tid & 63;
  const int m0 = blockIdx.y * 128, n0 = blockIdx.x * BN;
  const int srow = tid >> 3, schk = tid & 7;
  const int fr = lane & 15, fg = lane >> 4;

  f32x4 acc[2][NC];
  #pragma unroll
  for (int rt = 0; rt < 2; ++rt)
    #pragma unroll
    for (int ct = 0; ct < NC; ++ct) acc[rt][ct] = (f32x4){0.f, 0.f, 0.f, 0.f};

  bh8 av[4], bv[NB];
  #pragma unroll
  for (int p = 0; p < 4; ++p)
    av[p] = *reinterpret_cast<const bh8*>(A + (size_t)(m0 + srow + p * 32) * K + schk * 8);
  #pragma unroll
  for (int p = 0; p < NB; ++p) {
    const int nr = n0 + srow + p * 32;
    if (nr < N) bv[p] = *reinterpret_cast<const bh8*>(Bt + (size_t)nr * K + schk * 8);
    else        bv[p] = (bh8){0,0,0,0,0,0,0,0};
  }

  for (int k0 = 0; k0 < K; k0 += 64) {
    __syncthreads();
    #pragma unroll
    for (int p = 0; p < 4; ++p)
      *reinterpret_cast<bh8*>(As + (srow + p * 32) * LDK + schk * 8) = av[p];
    #pragma unroll
    for (int p = 0; p < NB; ++p)
      *reinterpret_cast<bh8*>(Bs + (srow + p * 32) * LDK + schk * 8) = bv[p];
    __syncthreads();
    if (k0 + 64 < K) {
      const int kn = k0 + 64 + schk * 8;
      #pragma unroll
      for (int p = 0; p < 4; ++p)
        av[p] = *reinterpret_cast<const bh8*>(A + (size_t)(m0 + srow + p * 32) * K + kn);
      #pragma unroll
      for (int p = 0; p < NB; ++p) {
        const int nr = n0 + srow + p * 32;
        if (nr < N) bv[p] = *reinterpret_cast<const bh8*>(Bt + (size_t)nr * K + kn);
      }
    }
    #pragma unroll
    for (int s = 0; s < 2; ++s) {
      bh8 af[2];
      #pragma unroll
      for (int rt = 0; rt < 2; ++rt)
        af[rt] = *reinterpret_cast<const bh8*>(As + (wid * 32 + rt * 16 + fr) * LDK + s * 32 + fg * 8);
      #pragma unroll
      for (int ct = 0; ct < NC; ++ct) {
        const bh8 bf_ = *reinterpret_cast<const bh8*>(Bs + (ct * 16 + fr) * LDK + s * 32 + fg * 8);
        #pragma unroll
        for (int rt = 0; rt < 2; ++rt)
          acc[rt][ct] = __builtin_amdgcn_mfma_f32_16x16x32_bf16(af[rt], bf_, acc[rt][ct], 0, 0, 0);
      }
    }
  }

  #pragma unroll
  for (int rt = 0; rt < 2; ++rt)
    #pragma unroll
    for (int ct = 0; ct < NC; ++ct) {
      const int col = n0 + ct * 16 + fr;
      if (col < N) {
        #pragma unroll
        for (int rr = 0; rr < 4; ++rr) {
          const int row = m0 + wid * 32 + rt * 16 + fg * 4 + rr;
          float v = acc[rt][ct][rr];
          if (EPI == 0) {
            ((float*)Cv)[(size_t)row * N + col] = v;
          } else {  // EPI 3: qkv scatter (q pre-scaled for exp2 softmax)
            const int part = col / 192, c2 = col - part * 192;
            if (part == 0) v *= ATT_SCALE_L2E;
            const int bb = row >> 9, tt = row & (SEQ - 1);
            const int hh = c2 >> 5, dd = c2 & (HSZ - 1);
            ((__hip_bfloat16*)Cv)[(size_t)part * BT * EMB +
                (((size_t)(bb * NH + hh)) * SEQ + tt) * HSZ + dd] = __float2bfloat16(v);
          }
        }
      }
    }
}

// ---------------------------------------------------------------- GEMM+res+LN, BM=32, 2 waves (last layer)
__global__ __launch_bounds__(128) void gemm_resln(
    const __hip_bfloat16* __restrict__ A, const __hip_bfloat16* __restrict__ Bt,
    float* __restrict__ X, __hip_bfloat16* __restrict__ Hout,
    const float* __restrict__ g, const float* __restrict__ b, int K) {
  constexpr int LDK = 72;
  __shared__ short As[32 * LDK];
  __shared__ short Bs[192 * LDK];
  const int tid = threadIdx.x;
  const int wid = tid >> 6, lane = tid & 63;
  const int m0 = blockIdx.x * 32;
  const int srow = tid >> 3, schk = tid & 7;
  const int fr = lane & 15, fg = lane >> 4;

  f32x4 acc[12];
  #pragma unroll
  for (int j = 0; j < 12; ++j) acc[j] = (f32x4){0.f, 0.f, 0.f, 0.f};

  bh8 av[2], bv[12];
  #pragma unroll
  for (int p = 0; p < 2; ++p)
    av[p] = *reinterpret_cast<const bh8*>(A + (size_t)(m0 + srow + p * 16) * K + schk * 8);
  #pragma unroll
  for (int p = 0; p < 12; ++p)
    bv[p] = *reinterpret_cast<const bh8*>(Bt + (size_t)(srow + p * 16) * K + schk * 8);

  for (int k0 = 0; k0 < K; k0 += 64) {
    __syncthreads();
    #pragma unroll
    for (int p = 0; p < 2; ++p)
      *reinterpret_cast<bh8*>(As + (srow + p * 16) * LDK + schk * 8) = av[p];
    #pragma unroll
    for (int p = 0; p < 12; ++p)
      *reinterpret_cast<bh8*>(Bs + (srow + p * 16) * LDK + schk * 8) = bv[p];
    __syncthreads();
    if (k0 + 64 < K) {
      const int kn = k0 + 64 + schk * 8;
      #pragma unroll
      for (int p = 0; p < 2; ++p)
        av[p] = *reinterpret_cast<const bh8*>(A + (size_t)(m0 + srow + p * 16) * K + kn);
      #pragma unroll
      for (int p = 0; p < 12; ++p)
        bv[p] = *reinterpret_cast<const bh8*>(Bt + (size_t)(srow + p * 16) * K + kn);
    }
    #pragma unroll
    for (int s = 0; s < 2; ++s) {
      const bh8 af = *reinterpret_cast<const bh8*>(As + (wid * 16 + fr) * LDK + s * 32 + fg * 8);
      #pragma unroll
      for (int j = 0; j < 12; ++j) {
        const bh8 bf_ = *reinterpret_cast<const bh8*>(Bs + (j * 16 + fr) * LDK + s * 32 + fg * 8);
        acc[j] = __builtin_amdgcn_mfma_f32_16x16x32_bf16(af, bf_, acc[j], 0, 0, 0);
      }
    }
  }

  #pragma unroll
  for (int rr = 0; rr < 4; ++rr) {
    const int row = m0 + wid * 16 + fg * 4 + rr;
    float v[12], sum = 0.f, sq = 0.f;
    #pragma unroll
    for (int j = 0; j < 12; ++j) {
      v[j] = acc[j][rr] + X[(size_t)row * EMB + j * 16 + fr];
      sum += v[j]; sq += v[j] * v[j];
    }
    #pragma unroll
    for (int o = 8; o; o >>= 1) {
      sum += __shfl_xor(sum, o);
      sq  += __shfl_xor(sq,  o);
    }
    const float mu = sum * (1.0f / (float)EMB);
    const float r  = rsqrtf(sq * (1.0f / (float)EMB) - mu * mu + 1e-5f);
    #pragma unroll
    for (int j = 0; j < 12; ++j) {
      const int col = j * 16 + fr;
      X[(size_t)row * EMB + col] = v[j];
      Hout[(size_t)row * EMB + col] = __float2bfloat16((v[j] - mu) * r * g[col] + b[col]);
    }
  }
}

// ---------------------------------------------------------------- fused resLN + follow-on GEMM
// phase1 (round-8 proven): X += A@B1t^T, h = LN -> LDS
// phase2 (no barriers): stream B2 frags direct from L2; P2==1: gelu->hid[768];
//                       P2==2: next-layer qkv scatter (q pre-scaled)
template<int P2>
__global__ __launch_bounds__(128) void resln_fused(
    const __hip_bfloat16* __restrict__ A, const __hip_bfloat16* __restrict__ B1t,
    float* __restrict__ X, const float* __restrict__ g, const float* __restrict__ b,
    int K1, const __hip_bfloat16* __restrict__ B2t,
    __hip_bfloat16* __restrict__ Out2) {
  constexpr int N2 = (P2 == 1) ? 768 : 576;
  constexpr int NT = N2 / 16;
  constexpr int LDK = 72;
  constexpr int LDH = 200;
  __shared__ short As[32 * LDK];     // 4.6 KB
  __shared__ short Bs[192 * LDK];    // 27.6 KB
  __shared__ short Hs[32 * LDH];     // 12.8 KB (disjoint from As/Bs)
  const int tid = threadIdx.x;       // 0..127, 2 waves
  const int wid = tid >> 6, lane = tid & 63;
  const int m0 = blockIdx.x * 32;
  const int srow = tid >> 3, schk = tid & 7;
  const int fr = lane & 15, fg = lane >> 4;

  // ---------------- phase 1
  f32x4 acc[12];
  #pragma unroll
  for (int j = 0; j < 12; ++j) acc[j] = (f32x4){0.f, 0.f, 0.f, 0.f};

  bh8 av[2], bv[12];
  #pragma unroll
  for (int p = 0; p < 2; ++p)
    av[p] = *reinterpret_cast<const bh8*>(A + (size_t)(m0 + srow + p * 16) * K1 + schk * 8);
  #pragma unroll
  for (int p = 0; p < 12; ++p)
    bv[p] = *reinterpret_cast<const bh8*>(B1t + (size_t)(srow + p * 16) * K1 + schk * 8);

  for (int k0 = 0; k0 < K1; k0 += 64) {
    __syncthreads();
    #pragma unroll
    for (int p = 0; p < 2; ++p)
      *reinterpret_cast<bh8*>(As + (srow + p * 16) * LDK + schk * 8) = av[p];
    #pragma unroll
    for (int p = 0; p < 12; ++p)
      *reinterpret_cast<bh8*>(Bs + (srow + p * 16) * LDK + schk * 8) = bv[p];
    __syncthreads();
    if (k0 + 64 < K1) {
      const int kn = k0 + 64 + schk * 8;
      #pragma unroll
      for (int p = 0; p < 2; ++p)
        av[p] = *reinterpret_cast<const bh8*>(A + (size_t)(m0 + srow + p * 16) * K1 + kn);
      #pragma unroll
      for (int p = 0; p < 12; ++p)
        bv[p] = *reinterpret_cast<const bh8*>(B1t + (size_t)(srow + p * 16) * K1 + kn);
    }
    #pragma unroll
    for (int s = 0; s < 2; ++s) {
      const bh8 af = *reinterpret_cast<const bh8*>(As + (wid * 16 + fr) * LDK + s * 32 + fg * 8);
      #pragma unroll
      for (int j = 0; j < 12; ++j) {
        const bh8 bf_ = *reinterpret_cast<const bh8*>(Bs + (j * 16 + fr) * LDK + s * 32 + fg * 8);
        acc[j] = __builtin_amdgcn_mfma_f32_16x16x32_bf16(af, bf_, acc[j], 0, 0, 0);
      }
    }
  }

  // residual + LN -> X (global) and Hs (LDS; disjoint array, no barrier needed before write)
  #pragma unroll
  for (int rr = 0; rr < 4; ++rr) {
    const int lrow = wid * 16 + fg * 4 + rr;
    const int row = m0 + lrow;
    float v[12], sum = 0.f, sq = 0.f;
    #pragma unroll
    for (int j = 0; j < 12; ++j) {
      v[j] = acc[j][rr] + X[(size_t)row * EMB + j * 16 + fr];
      sum += v[j]; sq += v[j] * v[j];
    }
    #pragma unroll
    for (int o = 8; o; o >>= 1) {
      sum += __shfl_xor(sum, o);
      sq  += __shfl_xor(sq,  o);
    }
    const float mu = sum * (1.0f / (float)EMB);
    const float r  = rsqrtf(sq * (1.0f / (float)EMB) - mu * mu + 1e-5f);
    #pragma unroll
    for (int j = 0; j < 12; ++j) {
      const int col = j * 16 + fr;
      X[(size_t)row * EMB + col] = v[j];
      Hs[lrow * LDH + col] = bf16s((v[j] - mu) * r * g[col] + b[col]);
    }
  }
  __syncthreads();   // Hs visible to both waves

  // ---------------- phase 2: h(LDS) @ B2t^T, B2 frags streamed from L2, no barriers
  bh8 af2[2][6];
  #pragma unroll
  for (int mt = 0; mt < 2; ++mt)
    #pragma unroll
    for (int kk = 0; kk < 6; ++kk)
      af2[mt][kk] = *reinterpret_cast<const bh8*>(Hs + (mt * 16 + fr) * LDH + kk * 32 + fg * 8);

  bh8 bcur[6], bnxt[6];
  #pragma unroll
  for (int kk = 0; kk < 6; ++kk)
    bcur[kk] = *reinterpret_cast<const bh8*>(B2t + (size_t)(wid * 16 + fr) * 192 + kk * 32 + fg * 8);

  for (int ntile = wid; ntile < NT; ntile += 2) {
    const int nnext = ntile + 2;
    if (nnext < NT) {
      #pragma unroll
      for (int kk = 0; kk < 6; ++kk)
        bnxt[kk] = *reinterpret_cast<const bh8*>(B2t + (size_t)(nnext * 16 + fr) * 192 + kk * 32 + fg * 8);
    }
    f32x4 a2[2];
    a2[0] = (f32x4){0.f, 0.f, 0.f, 0.f};
    a2[1] = (f32x4){0.f, 0.f, 0.f, 0.f};
    #pragma unroll
    for (int kk = 0; kk < 6; ++kk) {
      a2[0] = __builtin_amdgcn_mfma_f32_16x16x32_bf16(af2[0][kk], bcur[kk], a2[0], 0, 0, 0);
      a2[1] = __builtin_amdgcn_mfma_f32_16x16x32_bf16(af2[1][kk], bcur[kk], a2[1], 0, 0, 0);
    }
    const int col = ntile * 16 + fr;
    #pragma unroll
    for (int mt = 0; mt < 2; ++mt)
      #pragma unroll
      for (int rr = 0; rr < 4; ++rr) {
        const int row = m0 + mt * 16 + fg * 4 + rr;
        float v = a2[mt][rr];
        if (P2 == 1) {
          v = 0.5f * v * (1.0f + erff(v * 0.70710678118654752f));
          Out2[(size_t)row * 768 + col] = __float2bfloat16(v);
        } else {  // next-layer qkv scatter
          const int part = col / 192, c2 = col - part * 192;
          if (part == 0) v *= ATT_SCALE_L2E;
          const int bb = row >> 9, tt = row & (SEQ - 1);
          const int hh = c2 >> 5, dd = c2 & (HSZ - 1);
          Out2[(size_t)part * BT * EMB +
               (((size_t)(bb * NH + hh)) * SEQ + tt) * HSZ + dd] = __float2bfloat16(v);
        }
      }
    if (nnext < NT) {
      #pragma unroll
      for (int kk = 0; kk < 6; ++kk) bcur[kk] = bnxt[kk];
    }
  }
}

// ---------------------------------------------------------------- flash attention, KT=128, exp2 softmax
__global__ __launch_bounds__(256) void flash_attn(
    const __hip_bfloat16* __restrict__ qh, const __hip_bfloat16* __restrict__ kh,
    const __hip_bfloat16* __restrict__ vh, __hip_bfloat16* __restrict__ att) {
  constexpr int QT = 128, KT = 128;
  constexpr int LK = 40;
  constexpr int LS = 136;
  __shared__ __hip_bfloat16 Ks[KT * LK];
  __shared__ __hip_bfloat16 Vs[HSZ * LS];
  __shared__ __hip_bfloat16 Ps[4][32 * LS];
  const int qt = (SEQ / QT - 1) - blockIdx.x;  // heavy blocks first
  const int h = blockIdx.y, b = blockIdx.z;
  const int tid = threadIdx.x, wid = tid >> 6, lane = tid & 63;
  const int q0 = qt * QT;
  const size_t hb = ((size_t)(b * NH + h)) * SEQ * HSZ;
  const int fr = lane & 15, fg = lane >> 4;

  bh8 aq[2];
  #pragma unroll
  for (int rt = 0; rt < 2; ++rt)
    aq[rt] = *reinterpret_cast<const bh8*>(
        qh + hb + (size_t)(q0 + wid * 32 + rt * 16 + fr) * HSZ + fg * 8);

  f32x4 o[2][2];
  float lp[2][4];
  #pragma unroll
  for (int rt = 0; rt < 2; ++rt) {
    #pragma unroll
    for (int ct = 0; ct < 2; ++ct) o[rt][ct] = (f32x4){0.f, 0.f, 0.f, 0.f};
    #pragma unroll
    for (int rr = 0; rr < 4; ++rr) lp[rt][rr] = 0.f;
  }

  const int nt = qt + 1;
  const int sr = tid >> 1;
  const int dbase = (tid & 1) * 16;
  bh8 kv[2], vv[2];
  #pragma unroll
  for (int i = 0; i < 2; ++i) {
    kv[i] = *reinterpret_cast<const bh8*>(kh + hb + (size_t)sr * HSZ + dbase + i * 8);
    vv[i] = *reinterpret_cast<const bh8*>(vh + hb + (size_t)sr * HSZ + dbase + i * 8);
  }

  for (int it = 0; it < nt; ++it) {
    const int s0 = it * KT;
    __syncthreads();
    #pragma unroll
    for (int i = 0; i < 2; ++i) {
      const int d0 = dbase + i * 8;
      *reinterpret_cast<bh8*>(&Ks[sr * LK + d0]) = kv[i];
      short tmp[8]; *reinterpret_cast<bh8*>(tmp) = vv[i];
      #pragma unroll
      for (int j = 0; j < 8; ++j)
        Vs[(d0 + j) * LS + sr] = *reinterpret_cast<__hip_bfloat16*>(&tmp[j]);
    }
    __syncthreads();
    if (it + 1 < nt) {
      const size_t nb_ = hb + (size_t)(s0 + KT + sr) * HSZ + dbase;
      #pragma unroll
      for (int i = 0; i < 2; ++i) {
        kv[i] = *reinterpret_cast<const bh8*>(kh + nb_ + i * 8);
        vv[i] = *reinterpret_cast<const bh8*>(vh + nb_ + i * 8);
      }
    }

    f32x4 sfr[2][8];
    #pragma unroll
    for (int rt = 0; rt < 2; ++rt)
      #pragma unroll
      for (int st = 0; st < 8; ++st) {
        const bh8 bf_ = *reinterpret_cast<const bh8*>(&Ks[(st * 16 + fr) * LK + fg * 8]);
        sfr[rt][st] = __builtin_amdgcn_mfma_f32_16x16x32_bf16(
            aq[rt], bf_, (f32x4){0.f, 0.f, 0.f, 0.f}, 0, 0, 0);
      }

    __hip_bfloat16* Pw = Ps[wid];
    const bool diag = (s0 + KT - 1 > q0 + wid * 32);
    #pragma unroll
    for (int rt = 0; rt < 2; ++rt) {
      #pragma unroll
      for (int rr = 0; rr < 4; ++rr) {
        float pr[8];
        if (diag) {
          const int qa = q0 + wid * 32 + rt * 16 + fg * 4 + rr;
          #pragma unroll
          for (int st = 0; st < 8; ++st) {
            const int sa = s0 + st * 16 + fr;
            pr[st] = (sa > qa) ? 0.f : exp2f(sfr[rt][st][rr]);
          }
        } else {
          #pragma unroll
          for (int st = 0; st < 8; ++st) pr[st] = exp2f(sfr[rt][st][rr]);
        }
        float ls = 0.f;
        #pragma unroll
        for (int st = 0; st < 8; ++st) ls += pr[st];
        lp[rt][rr] += ls;
        #pragma unroll
        for (int st = 0; st < 8; ++st)
          Pw[(rt * 16 + fg * 4 + rr) * LS + st * 16 + fr] = __float2bfloat16(pr[st]);
      }
    }

    #pragma unroll
    for (int ks = 0; ks < 4; ++ks) {
      bh8 vb_[2];
      #pragma unroll
      for (int ct = 0; ct < 2; ++ct)
        vb_[ct] = *reinterpret_cast<const bh8*>(&Vs[(ct * 16 + fr) * LS + ks * 32 + fg * 8]);
      #pragma unroll
      for (int rt = 0; rt < 2; ++rt) {
        const bh8 pa = *reinterpret_cast<const bh8*>(&Pw[(rt * 16 + fr) * LS + ks * 32 + fg * 8]);
        #pragma unroll
        for (int ct = 0; ct < 2; ++ct)
          o[rt][ct] = __builtin_amdgcn_mfma_f32_16x16x32_bf16(pa, vb_[ct], o[rt][ct], 0, 0, 0);
      }
    }
  }

  #pragma unroll
  for (int rt = 0; rt < 2; ++rt)
    #pragma unroll
    for (int rr = 0; rr < 4; ++rr) {
      float s = lp[rt][rr];
      #pragma unroll
      for (int off = 8; off; off >>= 1) s += __shfl_xor(s, off);
      const float inv = 1.0f / s;
      const int qa = q0 + wid * 32 + rt * 16 + fg * 4 + rr;
      #pragma unroll
      for (int ct = 0; ct < 2; ++ct) {
        const int d = ct * 16 + fr;
        att[((size_t)(b * SEQ + qa)) * EMB + h * HSZ + d] =
            __float2bfloat16(o[rt][ct][rr] * inv);
      }
    }
}

// ---------------------------------------------------------------- launcher
extern "C" void kernel_launch(void* const* d_in, const int* in_sizes, int n_in,
                              void* d_out, int out_size, void* d_ws, size_t ws_size,
                              hipStream_t stream) {
  const int*   idx   = (const int*)  d_in[0];
  const float* tok   = (const float*)d_in[1];
  const float* Wq    = (const float*)d_in[2];
  const float* Wk    = (const float*)d_in[3];
  const float* Wv    = (const float*)d_in[4];
  const float* Wo    = (const float*)d_in[5];
  const float* W1    = (const float*)d_in[6];
  const float* W2    = (const float*)d_in[7];
  const float* ln1g  = (const float*)d_in[8];
  const float* ln1b  = (const float*)d_in[9];
  const float* ln2g  = (const float*)d_in[10];
  const float* ln2b  = (const float*)d_in[11];
  const float* lnfg  = (const float*)d_in[12];
  const float* lnfb  = (const float*)d_in[13];
  const float* Wlm   = (const float*)d_in[14];
  float* out = (float*)d_out;

  const size_t NTE = (size_t)BT * EMB;
  char* ws = (char*)d_ws;
  float* x   = (float*)ws;                         ws += NTE * 4;
  __hip_bfloat16* qh   = (__hip_bfloat16*)ws;      ws += NTE * 2 * 3;  // q,k,v contiguous
  __hip_bfloat16* h    = (__hip_bfloat16*)ws;      ws += NTE * 2;
  __hip_bfloat16* att  = (__hip_bfloat16*)ws;      ws += NTE * 2;
  __hip_bfloat16* hid  = (__hip_bfloat16*)ws;      ws += NTE * 4 * 2;
  __hip_bfloat16* wqkv = (__hip_bfloat16*)ws;      ws += (size_t)NL * 576 * EMB * 2;
  __hip_bfloat16* wot  = (__hip_bfloat16*)ws;      ws += (size_t)NL * EMB * EMB * 2;
  __hip_bfloat16* w1t  = (__hip_bfloat16*)ws;      ws += (size_t)NL * EMB * EMB * 4 * 2;
  __hip_bfloat16* w2t  = (__hip_bfloat16*)ws;      ws += (size_t)NL * EMB * EMB * 4 * 2;
  __hip_bfloat16* wlt  = (__hip_bfloat16*)ws;

  wprep<<<3816, 256, 0, stream>>>(Wq, Wk, Wv, Wo, W1, W2, Wlm,
                                  wqkv, wot, w1t, w2t, wlt);
  embed_ln<<<BT / 4, 256, 0, stream>>>(idx, tok, ln1g, ln1b, x, h);

  const dim3 gQKV(576 / 64, BT / 128);            // (9,128)
  const dim3 gV  ((VOCAB + 127) / 128, BT / 128); // (51,128)
  const dim3 gA  (SEQ / 128, NH, BATCH);          // (4,6,32)

  gemm_big<3, 64><<<gQKV, 256, 0, stream>>>(h, wqkv, qh, BT, 576, EMB);

  for (int l = 0; l < NL; ++l) {
    const size_t wo = (size_t)l * EMB * EMB;
    const size_t wm = (size_t)l * EMB * EMB * 4;
    flash_attn<<<gA, 256, 0, stream>>>(qh, qh + NTE, qh + 2 * NTE, att);
    // Wo-resLN fused with W1+GELU (no-barrier L2-streamed phase 2)
    resln_fused<1><<<BT / 32, 128, 0, stream>>>(
        att, wot + wo, x, ln2g + l * EMB, ln2b + l * EMB, EMB, w1t + wm, hid);
    if (l < NL - 1) {
      // W2-resLN fused with next-layer QKV
      resln_fused<2><<<BT / 32, 128, 0, stream>>>(
          hid, w2t + wm, x, ln1g + (l + 1) * EMB, ln1b + (l + 1) * EMB, EMB * 4,
          wqkv + (size_t)(l + 1) * 576 * EMB, qh);
    } else {
      gemm_resln<<<BT / 32, 128, 0, stream>>>(hid, w2t + wm, x, h, lnfg, lnfb, EMB * 4);
    }
  }

  gemm_big<0, 128><<<gV, 256, 0, stream>>>(h, wlt, out, BT, VOCAB, EMB);
}

// Round 15
// 710.955 us; speedup vs baseline: 2.7609x; 1.0951x over previous
//
#include <hip/hip_runtime.h>
#include <hip/hip_bf16.h>
#include <math.h>

#define VOCAB 6500
#define EMB   192
#define NH    6
#define NL    6
#define SEQ   512
#define BATCH 32
#define HSZ   32
#define BT    (BATCH*SEQ)   // 16384 tokens

typedef __attribute__((ext_vector_type(8))) short bh8;
typedef __attribute__((ext_vector_type(4))) float f32x4;

#define ATT_SCALE 0.07216878364870323f   // 192^-0.5

// ---------------------------------------------------------------- embed + PE + LN1(layer0)
__global__ __launch_bounds__(256) void embed_ln(
    const int* __restrict__ idx, const float* __restrict__ tok,
    const float* __restrict__ g, const float* __restrict__ b,
    float* __restrict__ x, __hip_bfloat16* __restrict__ h) {
  const int wid = threadIdx.x >> 6, lane = threadIdx.x & 63;
  const int bt = blockIdx.x * 4 + wid;
  const int t  = bt & (SEQ - 1);
  const int tokid = idx[bt];
  float v[3];
  #pragma unroll
  for (int i = 0; i < 3; ++i) {
    const int e = lane + i * 64;
    const int i2 = e & ~1;
    const float div = expf((float)i2 * (-9.210340371976184f / (float)EMB));
    const float ang = (float)t * div;
    const float pe  = (e & 1) ? cosf(ang) : sinf(ang);
    v[i] = tok[(size_t)tokid * EMB + e] + pe;
  }
  float s = v[0] + v[1] + v[2];
  #pragma unroll
  for (int o = 32; o; o >>= 1) s += __shfl_xor(s, o);
  const float mu = s * (1.0f / (float)EMB);
  float vs = 0.f;
  #pragma unroll
  for (int i = 0; i < 3; ++i) { const float d = v[i] - mu; vs += d * d; }
  #pragma unroll
  for (int o = 32; o; o >>= 1) vs += __shfl_xor(vs, o);
  const float r = rsqrtf(vs * (1.0f / (float)EMB) + 1e-5f);
  float* xr = x + (size_t)bt * EMB;
  __hip_bfloat16* hr = h + (size_t)bt * EMB;
  #pragma unroll
  for (int i = 0; i < 3; ++i) {
    const int e = lane + i * 64;
    xr[e] = v[i];
    hr[e] = __float2bfloat16((v[i] - mu) * r * g[e] + b[e]);
  }
}

// ---------------------------------------------------------------- unified weight prep (all casts, one dispatch)
// flat job table: [0,864) qkv/o; [864,1728) W1; [1728,2592) W2; [2592,3816) Wlm
__global__ __launch_bounds__(256) void wprep(
    const float* __restrict__ Wq, const float* __restrict__ Wk,
    const float* __restrict__ Wv, const float* __restrict__ Wo,
    const float* __restrict__ W1, const float* __restrict__ W2,
    const float* __restrict__ Wlm,
    __hip_bfloat16* __restrict__ wqkv, __hip_bfloat16* __restrict__ wot,
    __hip_bfloat16* __restrict__ w1t,  __hip_bfloat16* __restrict__ w2t,
    __hip_bfloat16* __restrict__ wlt) {
  __shared__ float t[32][33];
  const int id = blockIdx.x;
  const float* Ws; __hip_bfloat16* Wd; int K, N, bx, by;
  if (id < 864) {                      // Wq/Wk/Wv/Wo: 24 mats x 36 tiles
    const int z = id / 36, rem = id % 36;
    const int sel = z / NL, layer = z % NL;
    by = rem / 6; bx = rem % 6; K = 192; N = 192;
    const float* s4[4] = {Wq, Wk, Wv, Wo};
    Ws = s4[sel] + (size_t)layer * 192 * 192;
    Wd = (sel < 3) ? wqkv + ((size_t)layer * 576 + sel * 192) * 192
                   : wot  + (size_t)layer * 192 * 192;
  } else if (id < 1728) {              // W1: [192][768] -> [768][192]
    const int j = id - 864, layer = j / 144, rem = j % 144;
    bx = rem % 24; by = rem / 24; K = 192; N = 768;
    Ws = W1 + (size_t)layer * 192 * 768;
    Wd = w1t + (size_t)layer * 768 * 192;
  } else if (id < 2592) {              // W2: [768][192] -> [192][768]
    const int j = id - 1728, layer = j / 144, rem = j % 144;
    bx = rem % 6; by = rem / 6; K = 768; N = 192;
    Ws = W2 + (size_t)layer * 768 * 192;
    Wd = w2t + (size_t)layer * 192 * 768;
  } else {                             // Wlm: [192][6500] -> [6500][192]
    const int j = id - 2592;
    bx = j % 204; by = j / 204; K = 192; N = VOCAB;
    Ws = Wlm; Wd = wlt;
  }
  const int kt = by * 32, nt = bx * 32;
  const int tx = threadIdx.x & 31, ty = threadIdx.x >> 5;
  for (int i = ty; i < 32; i += 8) {
    const int k = kt + i, n = nt + tx;
    t[i][tx] = (k < K && n < N) ? Ws[(size_t)k * N + n] : 0.f;
  }
  __syncthreads();
  for (int i = ty; i < 32; i += 8) {
    const int n = nt + i, k = kt + tx;
    if (n < N && k < K) Wd[(size_t)n * K + k] = __float2bfloat16(t[tx][i]);
  }
}

// ---------------------------------------------------------------- big-tile GEMM (BM=128), prefetched
// EPI 0: f32 [M,N];  EPI 2: gelu->bf16 [M,N];  EPI 3: bf16 qkv scatter (q pre-scaled)
template<int EPI, int BN>
__global__ __launch_bounds__(256) void gemm_big(
    const __hip_bfloat16* __restrict__ A, const __hip_bfloat16* __restrict__ Bt,
    void* __restrict__ Cv, int M, int N, int K) {
  constexpr int LDK = 72;
  constexpr int NB = BN / 32;
  constexpr int NC = BN / 16;
  __shared__ short As[128 * LDK];
  __shared__ short Bs[BN * LDK];
  const int tid = threadIdx.x;
  const int wid = tid >> 6, lane = tid & 63;
  const int m0 = blockIdx.y * 128, n0 = blockIdx.x * BN;
  const int srow = tid >> 3, schk = tid & 7;
  const int fr = lane & 15, fg = lane >> 4;

  f32x4 acc[2][NC];
  #pragma unroll
  for (int rt = 0; rt < 2; ++rt)
    #pragma unroll
    for (int ct = 0; ct < NC; ++ct) acc[rt][ct] = (f32x4){0.f, 0.f, 0.f, 0.f};

  bh8 av[4], bv[NB];
  #pragma unroll
  for (int p = 0; p < 4; ++p)
    av[p] = *reinterpret_cast<const bh8*>(A + (size_t)(m0 + srow + p * 32) * K + schk * 8);
  #pragma unroll
  for (int p = 0; p < NB; ++p) {
    const int nr = n0 + srow + p * 32;
    if (nr < N) bv[p] = *reinterpret_cast<const bh8*>(Bt + (size_t)nr * K + schk * 8);
    else        bv[p] = (bh8){0,0,0,0,0,0,0,0};
  }

  for (int k0 = 0; k0 < K; k0 += 64) {
    __syncthreads();
    #pragma unroll
    for (int p = 0; p < 4; ++p)
      *reinterpret_cast<bh8*>(As + (srow + p * 32) * LDK + schk * 8) = av[p];
    #pragma unroll
    for (int p = 0; p < NB; ++p)
      *reinterpret_cast<bh8*>(Bs + (srow + p * 32) * LDK + schk * 8) = bv[p];
    __syncthreads();
    // prefetch next tile (issued before MFMA; latency hides under compute)
    if (k0 + 64 < K) {
      const int kn = k0 + 64 + schk * 8;
      #pragma unroll
      for (int p = 0; p < 4; ++p)
        av[p] = *reinterpret_cast<const bh8*>(A + (size_t)(m0 + srow + p * 32) * K + kn);
      #pragma unroll
      for (int p = 0; p < NB; ++p) {
        const int nr = n0 + srow + p * 32;
        if (nr < N) bv[p] = *reinterpret_cast<const bh8*>(Bt + (size_t)nr * K + kn);
      }
    }
    #pragma unroll
    for (int s = 0; s < 2; ++s) {
      bh8 af[2];
      #pragma unroll
      for (int rt = 0; rt < 2; ++rt)
        af[rt] = *reinterpret_cast<const bh8*>(As + (wid * 32 + rt * 16 + fr) * LDK + s * 32 + fg * 8);
      #pragma unroll
      for (int ct = 0; ct < NC; ++ct) {
        const bh8 bf_ = *reinterpret_cast<const bh8*>(Bs + (ct * 16 + fr) * LDK + s * 32 + fg * 8);
        #pragma unroll
        for (int rt = 0; rt < 2; ++rt)
          acc[rt][ct] = __builtin_amdgcn_mfma_f32_16x16x32_bf16(af[rt], bf_, acc[rt][ct], 0, 0, 0);
      }
    }
  }

  #pragma unroll
  for (int rt = 0; rt < 2; ++rt)
    #pragma unroll
    for (int ct = 0; ct < NC; ++ct) {
      const int col = n0 + ct * 16 + fr;
      if (col < N) {
        #pragma unroll
        for (int rr = 0; rr < 4; ++rr) {
          const int row = m0 + wid * 32 + rt * 16 + fg * 4 + rr;
          float v = acc[rt][ct][rr];
          if (EPI == 0) {
            ((float*)Cv)[(size_t)row * N + col] = v;
          } else if (EPI == 2) {
            v = 0.5f * v * (1.0f + erff(v * 0.70710678118654752f));
            ((__hip_bfloat16*)Cv)[(size_t)row * N + col] = __float2bfloat16(v);
          } else {  // EPI 3: qkv scatter, pre-scale q
            const int part = col / 192, c2 = col - part * 192;
            if (part == 0) v *= ATT_SCALE;
            const int bb = row >> 9, tt = row & (SEQ - 1);
            const int hh = c2 >> 5, dd = c2 & (HSZ - 1);
            ((__hip_bfloat16*)Cv)[(size_t)part * BT * EMB +
                (((size_t)(bb * NH + hh)) * SEQ + tt) * HSZ + dd] = __float2bfloat16(v);
          }
        }
      }
    }
}

// ---------------------------------------------------------------- GEMM+res+LN, BM=32, 2 waves, prefetched
// X += A@Bt^T (f32 in-place); Hout = LN(X)*g+b (bf16)
__global__ __launch_bounds__(128) void gemm_resln(
    const __hip_bfloat16* __restrict__ A, const __hip_bfloat16* __restrict__ Bt,
    float* __restrict__ X, __hip_bfloat16* __restrict__ Hout,
    const float* __restrict__ g, const float* __restrict__ b, int K) {
  constexpr int LDK = 72;
  __shared__ short As[32 * LDK];
  __shared__ short Bs[192 * LDK];
  const int tid = threadIdx.x;            // 0..127, 2 waves
  const int wid = tid >> 6, lane = tid & 63;
  const int m0 = blockIdx.x * 32;
  const int srow = tid >> 3, schk = tid & 7;   // srow 0..15
  const int fr = lane & 15, fg = lane >> 4;

  f32x4 acc[12];
  #pragma unroll
  for (int j = 0; j < 12; ++j) acc[j] = (f32x4){0.f, 0.f, 0.f, 0.f};

  bh8 av[2], bv[12];
  #pragma unroll
  for (int p = 0; p < 2; ++p)
    av[p] = *reinterpret_cast<const bh8*>(A + (size_t)(m0 + srow + p * 16) * K + schk * 8);
  #pragma unroll
  for (int p = 0; p < 12; ++p)
    bv[p] = *reinterpret_cast<const bh8*>(Bt + (size_t)(srow + p * 16) * K + schk * 8);

  for (int k0 = 0; k0 < K; k0 += 64) {
    __syncthreads();
    #pragma unroll
    for (int p = 0; p < 2; ++p)
      *reinterpret_cast<bh8*>(As + (srow + p * 16) * LDK + schk * 8) = av[p];
    #pragma unroll
    for (int p = 0; p < 12; ++p)
      *reinterpret_cast<bh8*>(Bs + (srow + p * 16) * LDK + schk * 8) = bv[p];
    __syncthreads();
    if (k0 + 64 < K) {
      const int kn = k0 + 64 + schk * 8;
      #pragma unroll
      for (int p = 0; p < 2; ++p)
        av[p] = *reinterpret_cast<const bh8*>(A + (size_t)(m0 + srow + p * 16) * K + kn);
      #pragma unroll
      for (int p = 0; p < 12; ++p)
        bv[p] = *reinterpret_cast<const bh8*>(Bt + (size_t)(srow + p * 16) * K + kn);
    }
    #pragma unroll
    for (int s = 0; s < 2; ++s) {
      const bh8 af = *reinterpret_cast<const bh8*>(As + (wid * 16 + fr) * LDK + s * 32 + fg * 8);
      #pragma unroll
      for (int j = 0; j < 12; ++j) {
        const bh8 bf_ = *reinterpret_cast<const bh8*>(Bs + (j * 16 + fr) * LDK + s * 32 + fg * 8);
        acc[j] = __builtin_amdgcn_mfma_f32_16x16x32_bf16(af, bf_, acc[j], 0, 0, 0);
      }
    }
  }

  #pragma unroll
  for (int rr = 0; rr < 4; ++rr) {
    const int row = m0 + wid * 16 + fg * 4 + rr;
    float v[12], sum = 0.f, sq = 0.f;
    #pragma unroll
    for (int j = 0; j < 12; ++j) {
      v[j] = acc[j][rr] + X[(size_t)row * EMB + j * 16 + fr];
      sum += v[j]; sq += v[j] * v[j];
    }
    #pragma unroll
    for (int o = 8; o; o >>= 1) {
      sum += __shfl_xor(sum, o);
      sq  += __shfl_xor(sq,  o);
    }
    const float mu = sum * (1.0f / (float)EMB);
    const float r  = rsqrtf(sq * (1.0f / (float)EMB) - mu * mu + 1e-5f);
    #pragma unroll
    for (int j = 0; j < 12; ++j) {
      const int col = j * 16 + fr;
      X[(size_t)row * EMB + col] = v[j];
      Hout[(size_t)row * EMB + col] = __float2bfloat16((v[j] - mu) * r * g[col] + b[col]);
    }
  }
}

// ---------------------------------------------------------------- flash attention, KT=128, prefetched
// q pre-scaled by ATT_SCALE; heavy-first block ordering; setprio around MFMA clusters (T5)
__global__ __launch_bounds__(256) void flash_attn(
    const __hip_bfloat16* __restrict__ qh, const __hip_bfloat16* __restrict__ kh,
    const __hip_bfloat16* __restrict__ vh, __hip_bfloat16* __restrict__ att) {
  constexpr int QT = 128, KT = 128;
  constexpr int LK = 40;    // Ks row stride (80B, odd x16B -> conflict-free)
  constexpr int LS = 136;   // Vs/Ps row stride (272B, odd x16B)
  __shared__ __hip_bfloat16 Ks[KT * LK];      // [s][d]  10.2 KB
  __shared__ __hip_bfloat16 Vs[HSZ * LS];     // [d][s]   8.7 KB
  __shared__ __hip_bfloat16 Ps[4][32 * LS];   // per-wave P [q][s] 34.8 KB
  const int qt = (SEQ / QT - 1) - blockIdx.x;  // heavy blocks dispatch first
  const int h = blockIdx.y, b = blockIdx.z;
  const int tid = threadIdx.x, wid = tid >> 6, lane = tid & 63;
  const int q0 = qt * QT;
  const size_t hb = ((size_t)(b * NH + h)) * SEQ * HSZ;
  const int fr = lane & 15, fg = lane >> 4;

  bh8 aq[2];
  #pragma unroll
  for (int rt = 0; rt < 2; ++rt)
    aq[rt] = *reinterpret_cast<const bh8*>(
        qh + hb + (size_t)(q0 + wid * 32 + rt * 16 + fr) * HSZ + fg * 8);

  f32x4 o[2][2];
  float lp[2][4];
  #pragma unroll
  for (int rt = 0; rt < 2; ++rt) {
    #pragma unroll
    for (int ct = 0; ct < 2; ++ct) o[rt][ct] = (f32x4){0.f, 0.f, 0.f, 0.f};
    #pragma unroll
    for (int rr = 0; rr < 4; ++rr) lp[rt][rr] = 0.f;
  }

  const int nt = qt + 1;
  const int sr = tid >> 1;               // 0..127
  const int dbase = (tid & 1) * 16;      // 0 / 16
  bh8 kv[2], vv[2];
  #pragma unroll
  for (int i = 0; i < 2; ++i) {
    kv[i] = *reinterpret_cast<const bh8*>(kh + hb + (size_t)sr * HSZ + dbase + i * 8);
    vv[i] = *reinterpret_cast<const bh8*>(vh + hb + (size_t)sr * HSZ + dbase + i * 8);
  }

  for (int it = 0; it < nt; ++it) {
    const int s0 = it * KT;
    __syncthreads();
    #pragma unroll
    for (int i = 0; i < 2; ++i) {
      const int d0 = dbase + i * 8;
      *reinterpret_cast<bh8*>(&Ks[sr * LK + d0]) = kv[i];
      short tmp[8]; *reinterpret_cast<bh8*>(tmp) = vv[i];
      #pragma unroll
      for (int j = 0; j < 8; ++j)
        Vs[(d0 + j) * LS + sr] = *reinterpret_cast<__hip_bfloat16*>(&tmp[j]);
    }
    __syncthreads();
    if (it + 1 < nt) {
      const size_t nb_ = hb + (size_t)(s0 + KT + sr) * HSZ + dbase;
      #pragma unroll
      for (int i = 0; i < 2; ++i) {
        kv[i] = *reinterpret_cast<const bh8*>(kh + nb_ + i * 8);
        vv[i] = *reinterpret_cast<const bh8*>(vh + nb_ + i * 8);
      }
    }

    // S = Q K^T  (8 s-tiles of 16)
    f32x4 sfr[2][8];
    __builtin_amdgcn_s_setprio(1);
    #pragma unroll
    for (int rt = 0; rt < 2; ++rt)
      #pragma unroll
      for (int st = 0; st < 8; ++st) {
        const bh8 bf_ = *reinterpret_cast<const bh8*>(&Ks[(st * 16 + fr) * LK + fg * 8]);
        sfr[rt][st] = __builtin_amdgcn_mfma_f32_16x16x32_bf16(
            aq[rt], bf_, (f32x4){0.f, 0.f, 0.f, 0.f}, 0, 0, 0);
      }
    __builtin_amdgcn_s_setprio(0);

    // exp (no max subtraction: scores O(1)); per-thread partial row sums
    __hip_bfloat16* Pw = Ps[wid];
    const bool diag = (s0 + KT - 1 > q0 + wid * 32);
    #pragma unroll
    for (int rt = 0; rt < 2; ++rt) {
      #pragma unroll
      for (int rr = 0; rr < 4; ++rr) {
        float pr[8];
        if (diag) {
          const int qa = q0 + wid * 32 + rt * 16 + fg * 4 + rr;
          #pragma unroll
          for (int st = 0; st < 8; ++st) {
            const int sa = s0 + st * 16 + fr;
            pr[st] = (sa > qa) ? 0.f : __expf(sfr[rt][st][rr]);
          }
        } else {
          #pragma unroll
          for (int st = 0; st < 8; ++st) pr[st] = __expf(sfr[rt][st][rr]);
        }
        float ls = 0.f;
        #pragma unroll
        for (int st = 0; st < 8; ++st) ls += pr[st];
        lp[rt][rr] += ls;
        #pragma unroll
        for (int st = 0; st < 8; ++st)
          Pw[(rt * 16 + fg * 4 + rr) * LS + st * 16 + fr] = __float2bfloat16(pr[st]);
      }
    }

    // O += P V  (K=128 -> 4 k-steps)
    __builtin_amdgcn_s_setprio(1);
    #pragma unroll
    for (int ks = 0; ks < 4; ++ks) {
      bh8 vb_[2];
      #pragma unroll
      for (int ct = 0; ct < 2; ++ct)
        vb_[ct] = *reinterpret_cast<const bh8*>(&Vs[(ct * 16 + fr) * LS + ks * 32 + fg * 8]);
      #pragma unroll
      for (int rt = 0; rt < 2; ++rt) {
        const bh8 pa = *reinterpret_cast<const bh8*>(&Pw[(rt * 16 + fr) * LS + ks * 32 + fg * 8]);
        #pragma unroll
        for (int ct = 0; ct < 2; ++ct)
          o[rt][ct] = __builtin_amdgcn_mfma_f32_16x16x32_bf16(pa, vb_[ct], o[rt][ct], 0, 0, 0);
      }
    }
    __builtin_amdgcn_s_setprio(0);
  }

  // final row-sum reduce + epilogue
  #pragma unroll
  for (int rt = 0; rt < 2; ++rt)
    #pragma unroll
    for (int rr = 0; rr < 4; ++rr) {
      float s = lp[rt][rr];
      #pragma unroll
      for (int off = 8; off; off >>= 1) s += __shfl_xor(s, off);
      const float inv = 1.0f / s;
      const int qa = q0 + wid * 32 + rt * 16 + fg * 4 + rr;
      #pragma unroll
      for (int ct = 0; ct < 2; ++ct) {
        const int d = ct * 16 + fr;
        att[((size_t)(b * SEQ + qa)) * EMB + h * HSZ + d] =
            __float2bfloat16(o[rt][ct][rr] * inv);
      }
    }
}

// ---------------------------------------------------------------- launcher
extern "C" void kernel_launch(void* const* d_in, const int* in_sizes, int n_in,
                              void* d_out, int out_size, void* d_ws, size_t ws_size,
                              hipStream_t stream) {
  const int*   idx   = (const int*)  d_in[0];
  const float* tok   = (const float*)d_in[1];
  const float* Wq    = (const float*)d_in[2];
  const float* Wk    = (const float*)d_in[3];
  const float* Wv    = (const float*)d_in[4];
  const float* Wo    = (const float*)d_in[5];
  const float* W1    = (const float*)d_in[6];
  const float* W2    = (const float*)d_in[7];
  const float* ln1g  = (const float*)d_in[8];
  const float* ln1b  = (const float*)d_in[9];
  const float* ln2g  = (const float*)d_in[10];
  const float* ln2b  = (const float*)d_in[11];
  const float* lnfg  = (const float*)d_in[12];
  const float* lnfb  = (const float*)d_in[13];
  const float* Wlm   = (const float*)d_in[14];
  float* out = (float*)d_out;

  const size_t NTE = (size_t)BT * EMB;
  char* ws = (char*)d_ws;
  float* x   = (float*)ws;                         ws += NTE * 4;
  __hip_bfloat16* qh   = (__hip_bfloat16*)ws;      ws += NTE * 2 * 3;  // q,k,v contiguous
  __hip_bfloat16* h    = (__hip_bfloat16*)ws;      ws += NTE * 2;
  __hip_bfloat16* att  = (__hip_bfloat16*)ws;      ws += NTE * 2;
  __hip_bfloat16* hid  = (__hip_bfloat16*)ws;      ws += NTE * 4 * 2;
  __hip_bfloat16* wqkv = (__hip_bfloat16*)ws;      ws += (size_t)NL * 576 * EMB * 2;
  __hip_bfloat16* wot  = (__hip_bfloat16*)ws;      ws += (size_t)NL * EMB * EMB * 2;
  __hip_bfloat16* w1t  = (__hip_bfloat16*)ws;      ws += (size_t)NL * EMB * EMB * 4 * 2;
  __hip_bfloat16* w2t  = (__hip_bfloat16*)ws;      ws += (size_t)NL * EMB * EMB * 4 * 2;
  __hip_bfloat16* wlt  = (__hip_bfloat16*)ws;

  wprep<<<3816, 256, 0, stream>>>(Wq, Wk, Wv, Wo, W1, W2, Wlm,
                                  wqkv, wot, w1t, w2t, wlt);
  embed_ln<<<BT / 4, 256, 0, stream>>>(idx, tok, ln1g, ln1b, x, h);

  const dim3 gQKV(576 / 64, BT / 128);            // (9,128)
  const dim3 gM  (EMB * 4 / 64, BT / 128);        // (12,128)
  const dim3 gV  ((VOCAB + 127) / 128, BT / 128); // (51,128)
  const dim3 gA  (SEQ / 128, NH, BATCH);          // (4,6,32)

  for (int l = 0; l < NL; ++l) {
    const size_t wo = (size_t)l * EMB * EMB;
    const size_t wm = (size_t)l * EMB * EMB * 4;
    gemm_big<3, 64><<<gQKV, 256, 0, stream>>>(h, wqkv + (size_t)l * 576 * EMB, qh, BT, 576, EMB);
    flash_attn<<<gA, 256, 0, stream>>>(qh, qh + NTE, qh + 2 * NTE, att);
    gemm_resln<<<BT / 32, 128, 0, stream>>>(att, wot + wo, x, h,
                                            ln2g + l * EMB, ln2b + l * EMB, EMB);
    gemm_big<2, 64><<<gM, 256, 0, stream>>>(h, w1t + wm, hid, BT, EMB * 4, EMB);
    const float* ng = (l == NL - 1) ? lnfg : ln1g + (l + 1) * EMB;
    const float* nb = (l == NL - 1) ? lnfb : ln1b + (l + 1) * EMB;
    gemm_resln<<<BT / 32, 128, 0, stream>>>(hid, w2t + wm, x, h, ng, nb, EMB * 4);
  }

  gemm_big<0, 128><<<gV, 256, 0, stream>>>(h, wlt, out, BT, VOCAB, EMB);
}